// Round 5
// baseline (691.789 us; speedup 1.0000x reference)
//
#include <hip/hip_runtime.h>
#include <hip/hip_bf16.h>
#include <math.h>

#define B_ 4
#define S_ 2048
#define HID_ 768
#define NH_ 12
#define HD_ 64

typedef short bf16x8 __attribute__((ext_vector_type(8)));
typedef short bf16x4 __attribute__((ext_vector_type(4)));
typedef float f32x4 __attribute__((ext_vector_type(4)));
typedef unsigned short u16;
typedef unsigned int uu32;

#define QSCALE 0.18033688011112042f   /* 0.125 * log2(e) */
#define LOG2E  1.4426950408889634f

__device__ __forceinline__ u16 f2bf(float f) {
  union { float f; unsigned u; } x; x.f = f;
  unsigned u = x.u;
  u += 0x7FFFu + ((u >> 16) & 1u);   // round-to-nearest-even
  return (u16)(u >> 16);
}

__device__ __forceinline__ float exp2_fast(float x) {
  float r;
  asm("v_exp_f32 %0, %1" : "=v"(r) : "v"(x));
  return r;
}

__device__ __forceinline__ uu32 cvt_pk_bf16(float lo, float hi) {
  uu32 r;
  asm("v_cvt_pk_bf16_f32 %0, %1, %2" : "=v"(r) : "v"(lo), "v"(hi));
  return r;
}

// ---------------- cast hidden fp32 -> bf16 ----------------
__global__ void cast_x(const float* __restrict__ x, u16* __restrict__ xb, int n) {
  int i = (blockIdx.x * 256 + threadIdx.x) * 4;
  if (i >= n) return;
  float4 v = *(const float4*)(x + i);
  ushort4 o;
  o.x = f2bf(v.x); o.y = f2bf(v.y); o.z = f2bf(v.z); o.w = f2bf(v.w);
  *(ushort4*)(xb + i) = o;
}

// ---------------- mask * log2e ----------------
__global__ void mask_scale(const float* __restrict__ m, float* __restrict__ o, int n) {
  int i = blockIdx.x * 256 + threadIdx.x;
  if (i < n) o[i] = m[i] * LOG2E;
}

// ------------- transpose + cast W[k][n] -> Wt[n][k] bf16 -------------
__global__ void wtrans(const float* __restrict__ Wq, const float* __restrict__ Wk,
                       const float* __restrict__ Wv, u16* __restrict__ wt) {
  const float* W = blockIdx.z == 0 ? Wq : (blockIdx.z == 1 ? Wk : Wv);
  u16* out = wt + (size_t)blockIdx.z * HID_ * HID_;
  __shared__ float t[32][33];
  int tx = threadIdx.x & 31, ty = threadIdx.x >> 5;   // 32 x 8
  int k0 = blockIdx.x * 32, n0 = blockIdx.y * 32;
#pragma unroll
  for (int i = 0; i < 4; i++)
    t[ty + 8 * i][tx] = W[(k0 + ty + 8 * i) * HID_ + n0 + tx];
  __syncthreads();
#pragma unroll
  for (int i = 0; i < 4; i++)
    out[(n0 + ty + 8 * i) * HID_ + k0 + tx] = f2bf(t[tx][ty + 8 * i]);
}

// ---------------- QKV projection GEMM ----------------
// z=0: Q (pre-scaled by 0.125*log2e), z=1: K, both [b,h,s,d].
// z=2: V written DIRECTLY transposed as Vt [b,h,d,s].
__global__ __launch_bounds__(256) void qkv_gemm(
    const u16* __restrict__ xb, const u16* __restrict__ wt_all,
    const float* __restrict__ bq, const float* __restrict__ bk,
    const float* __restrict__ bv,
    u16* __restrict__ q, u16* __restrict__ k_, u16* __restrict__ vt) {
  int z = blockIdx.z;
  const u16* wt = wt_all + (size_t)z * HID_ * HID_;
  const float* bias = z == 0 ? bq : (z == 1 ? bk : bv);

  int l = threadIdx.x & 63, w = threadIdx.x >> 6;
  int lr = l & 15, lg = l >> 4;
  int m0 = blockIdx.x * 128 + w * 32;
  int n0 = blockIdx.y * 64;

  f32x4 acc[2][4] = {};
  const u16* arow0 = xb + (size_t)(m0 + lr) * HID_ + 8 * lg;
  const u16* arow1 = arow0 + 16 * HID_;
  const u16* brow[4];
#pragma unroll
  for (int nt = 0; nt < 4; nt++)
    brow[nt] = wt + (size_t)(n0 + 16 * nt + lr) * HID_ + 8 * lg;

#pragma unroll 4
  for (int kk = 0; kk < HID_; kk += 32) {
    bf16x8 a0 = *(const bf16x8*)(arow0 + kk);
    bf16x8 a1 = *(const bf16x8*)(arow1 + kk);
#pragma unroll
    for (int nt = 0; nt < 4; nt++) {
      bf16x8 b = *(const bf16x8*)(brow[nt] + kk);
      acc[0][nt] = __builtin_amdgcn_mfma_f32_16x16x32_bf16(a0, b, acc[0][nt], 0, 0, 0);
      acc[1][nt] = __builtin_amdgcn_mfma_f32_16x16x32_bf16(a1, b, acc[1][nt], 0, 0, 0);
    }
  }

  int h = blockIdx.y;
  if (z == 2) {
#pragma unroll
    for (int mt = 0; mt < 2; mt++)
#pragma unroll
      for (int nt = 0; nt < 4; nt++) {
        float bval = bias[n0 + 16 * nt + lr];
        int m = m0 + 16 * mt + 4 * lg;
        int bidx = m >> 11, s = m & 2047;
        int d = 16 * nt + lr;
        ushort4 pk;
        pk.x = f2bf(acc[mt][nt][0] + bval);
        pk.y = f2bf(acc[mt][nt][1] + bval);
        pk.z = f2bf(acc[mt][nt][2] + bval);
        pk.w = f2bf(acc[mt][nt][3] + bval);
        *(ushort4*)(vt + ((size_t)(bidx * NH_ + h) * HD_ + d) * S_ + s) = pk;
      }
  } else {
    u16* out = z == 0 ? q : k_;
    float osc = z == 0 ? QSCALE : 1.0f;
#pragma unroll
    for (int mt = 0; mt < 2; mt++)
#pragma unroll
      for (int nt = 0; nt < 4; nt++) {
        float bval = bias[n0 + 16 * nt + lr];
#pragma unroll
        for (int r = 0; r < 4; r++) {
          int m = m0 + 16 * mt + 4 * lg + r;
          int bidx = m >> 11, s = m & 2047;
          out[(((size_t)(bidx * NH_ + h)) * S_ + s) * HD_ + 16 * nt + lr] =
              f2bf((acc[mt][nt][r] + bval) * osc);
        }
      }
  }
}

// ---------------- flash attention: swapped QK + shuffle-free PV ----------------
// 16 q-rows per wave, 64 per block, grid 1536 (6 blocks/CU).
// Straight-line loop body (no defer-max branch) so the compiler can
// software-pipeline loads across the back-edge.
// PV contraction permutation pi(h2, 8*lg+j) = 16*(2h2+(j>>2)) + 4*lg + (j&3):
// P^T B-fragment = lane's OWN QK output regs (cvt_pk only, no cross-lane),
// V^T A-fragment = four 8B loads at permuted columns.
__global__ __launch_bounds__(256) void attn5(
    const u16* __restrict__ q, const u16* __restrict__ k_,
    const u16* __restrict__ vt, const float* __restrict__ mask,
    float* __restrict__ out) {
  int id = blockIdx.x;
  int xcd = id & 7, ii = id >> 3;          // 192 blocks per XCD
  int bh = xcd * 6 + (ii >> 5);            // 6 heads per XCD -> K/V L2-resident
  int qb = ii & 31;
  int l = threadIdx.x & 63, w = threadIdx.x >> 6;
  int lr = l & 15, lg = l >> 4;
  int bidx = bh / NH_, h = bh % NH_;
  int q0 = qb * 64 + w * 16;

  __shared__ __align__(16) float ct_all[4][16 * 68];
  float* ct = ct_all[w];

  const u16* qbase = q + ((size_t)bh * S_ + q0) * HD_;
  const u16* kbase = k_ + (size_t)bh * S_ * HD_;
  const u16* vtb = vt + (size_t)bh * HD_ * S_;
  const float* mrow = mask + (size_t)bidx * S_;

  bf16x8 aq[2];
#pragma unroll
  for (int h2 = 0; h2 < 2; h2++)
    aq[h2] = *(const bf16x8*)(qbase + (size_t)lr * HD_ + 8 * lg + 32 * h2);

  f32x4 ctx[4] = {};
  float mrun = -INFINITY;
  float lpart = 0.f;   // per-lane-group partial denominator

  for (int kb = 0; kb < S_; kb += 64) {
    // K fragments (A-operand rows = kv)
    bf16x8 kf[4][2];
#pragma unroll
    for (int nt = 0; nt < 4; nt++) {
      const u16* kr = kbase + (size_t)(kb + 16 * nt + lr) * HD_ + 8 * lg;
      kf[nt][0] = *(const bf16x8*)(kr);
      kf[nt][1] = *(const bf16x8*)(kr + 32);
    }

    // QK^T swapped: sc[nt][r] = P^T[kb+16nt+4lg+r][q0+lr] (log2 domain)
    f32x4 sc[4] = {};
#pragma unroll
    for (int nt = 0; nt < 4; nt++) {
      sc[nt] = __builtin_amdgcn_mfma_f32_16x16x32_bf16(kf[nt][0], aq[0], sc[nt], 0, 0, 0);
      sc[nt] = __builtin_amdgcn_mfma_f32_16x16x32_bf16(kf[nt][1], aq[1], sc[nt], 0, 0, 0);
    }

    // V^T A-fragments at permuted columns
    union { bf16x8 v; bf16x4 h[2]; } vf[4][2];
#pragma unroll
    for (int nt = 0; nt < 4; nt++) {
      const u16* vr = vtb + (size_t)(16 * nt + lr) * S_ + kb + 4 * lg;
      vf[nt][0].h[0] = *(const bf16x4*)(vr);
      vf[nt][0].h[1] = *(const bf16x4*)(vr + 16);
      vf[nt][1].h[0] = *(const bf16x4*)(vr + 32);
      vf[nt][1].h[1] = *(const bf16x4*)(vr + 48);
    }

    f32x4 mk[4];
#pragma unroll
    for (int nt = 0; nt < 4; nt++)
      mk[nt] = *(const f32x4*)(mrow + kb + 16 * nt + 4 * lg);

#pragma unroll
    for (int nt = 0; nt < 4; nt++)
#pragma unroll
      for (int r = 0; r < 4; r++)
        sc[nt][r] = sc[nt][r] + mk[nt][r];

    // online softmax (always-rescale, branch-free)
    float m0_ = fmaxf(fmaxf(sc[0][0], sc[0][1]), fmaxf(sc[0][2], sc[0][3]));
    float m1_ = fmaxf(fmaxf(sc[1][0], sc[1][1]), fmaxf(sc[1][2], sc[1][3]));
    float m2_ = fmaxf(fmaxf(sc[2][0], sc[2][1]), fmaxf(sc[2][2], sc[2][3]));
    float m3_ = fmaxf(fmaxf(sc[3][0], sc[3][1]), fmaxf(sc[3][2], sc[3][3]));
    float vmax = fmaxf(fmaxf(m0_, m1_), fmaxf(m2_, m3_));
    vmax = fmaxf(vmax, __shfl_xor(vmax, 16));
    vmax = fmaxf(vmax, __shfl_xor(vmax, 32));

    float mnew = fmaxf(mrun, vmax);
    float scl = exp2_fast(mrun - mnew);
    mrun = mnew;
    lpart *= scl;

    float psum = 0.f;
#pragma unroll
    for (int nt = 0; nt < 4; nt++)
#pragma unroll
      for (int r = 0; r < 4; r++) {
        sc[nt][r] = exp2_fast(sc[nt][r] - mnew);
        psum += sc[nt][r];
      }
    lpart += psum;

#pragma unroll
    for (int nt = 0; nt < 4; nt++)
      ctx[nt] *= scl;

    // B-fragment = own registers under pi (no cross-lane)
    union { bf16x8 v; uu32 u[4]; } pb[2];
#pragma unroll
    for (int h2 = 0; h2 < 2; h2++) {
      pb[h2].u[0] = cvt_pk_bf16(sc[2 * h2][0], sc[2 * h2][1]);
      pb[h2].u[1] = cvt_pk_bf16(sc[2 * h2][2], sc[2 * h2][3]);
      pb[h2].u[2] = cvt_pk_bf16(sc[2 * h2 + 1][0], sc[2 * h2 + 1][1]);
      pb[h2].u[3] = cvt_pk_bf16(sc[2 * h2 + 1][2], sc[2 * h2 + 1][3]);
    }

    // PV: ctx^T[d][q] += V^T[d][pi(kv)] * P^T[pi(kv)][q]
#pragma unroll
    for (int nt = 0; nt < 4; nt++) {
      ctx[nt] = __builtin_amdgcn_mfma_f32_16x16x32_bf16(vf[nt][0].v, pb[0].v, ctx[nt], 0, 0, 0);
      ctx[nt] = __builtin_amdgcn_mfma_f32_16x16x32_bf16(vf[nt][1].v, pb[1].v, ctx[nt], 0, 0, 0);
    }
  }

  // epilogue: reduce lpart across groups, ctx^T -> LDS -> coalesced stores
  float lrun = lpart;
  lrun += __shfl_xor(lrun, 16);
  lrun += __shfl_xor(lrun, 32);
  float inv = 1.f / lrun;
#pragma unroll
  for (int nt = 0; nt < 4; nt++) {
    f32x4 vv = ctx[nt] * inv;
    *(f32x4*)(ct + lr * 68 + 16 * nt + 4 * lg) = vv;   // ct[q=lr][d]
  }
  float* ob = out + ((size_t)bidx * S_ + q0) * HID_ + h * HD_;
#pragma unroll
  for (int i = 0; i < 16; i++)
    ob[(size_t)i * HID_ + l] = ct[i * 68 + l];
}

extern "C" void kernel_launch(void* const* d_in, const int* in_sizes, int n_in,
                              void* d_out, int out_size, void* d_ws, size_t ws_size,
                              hipStream_t stream) {
  const float* x    = (const float*)d_in[0];
  const float* mask = (const float*)d_in[1];
  const float* Wq   = (const float*)d_in[2];
  const float* bq   = (const float*)d_in[3];
  const float* Wk   = (const float*)d_in[4];
  const float* bk   = (const float*)d_in[5];
  const float* Wv   = (const float*)d_in[6];
  const float* bv   = (const float*)d_in[7];
  float* out = (float*)d_out;

  char* ws = (char*)d_ws;
  const size_t SZ_X  = (size_t)B_ * S_ * HID_ * 2;
  const size_t SZ_W  = (size_t)3 * HID_ * HID_ * 2;
  u16* xb = (u16*)ws;
  u16* wt = (u16*)(ws + SZ_X);
  u16* q  = (u16*)(ws + SZ_X + SZ_W);
  u16* k  = (u16*)(ws + SZ_X + SZ_W + SZ_X);
  u16* vt = (u16*)(ws + SZ_X + SZ_W + 2 * SZ_X);
  float* mskl = (float*)(ws + SZ_X + SZ_W + 3 * SZ_X);

  int n = B_ * S_ * HID_;
  hipLaunchKernelGGL(cast_x, dim3(n / 1024), dim3(256), 0, stream, x, xb, n);
  hipLaunchKernelGGL(mask_scale, dim3(B_ * S_ / 256), dim3(256), 0, stream,
                     mask, mskl, B_ * S_);
  hipLaunchKernelGGL(wtrans, dim3(24, 24, 3), dim3(256), 0, stream, Wq, Wk, Wv, wt);
  hipLaunchKernelGGL(qkv_gemm, dim3(64, 12, 3), dim3(256), 0, stream,
                     xb, wt, bq, bk, bv, q, k, vt);
  hipLaunchKernelGGL(attn5, dim3(1536), dim3(256), 0, stream, q, k, vt, mskl, out);
}

// Round 6
// 259.396 us; speedup vs baseline: 2.6669x; 2.6669x over previous
//
#include <hip/hip_runtime.h>
#include <hip/hip_bf16.h>
#include <math.h>

#define B_ 4
#define S_ 2048
#define HID_ 768
#define NH_ 12
#define HD_ 64

typedef short bf16x8 __attribute__((ext_vector_type(8)));
typedef short bf16x4 __attribute__((ext_vector_type(4)));
typedef float f32x4 __attribute__((ext_vector_type(4)));
typedef unsigned short u16;
typedef unsigned int uu32;

#define QSCALE 0.18033688011112042f   /* 0.125 * log2(e) */
#define LOG2E  1.4426950408889634f

__device__ __forceinline__ u16 f2bf(float f) {
  union { float f; unsigned u; } x; x.f = f;
  unsigned u = x.u;
  u += 0x7FFFu + ((u >> 16) & 1u);   // round-to-nearest-even
  return (u16)(u >> 16);
}

__device__ __forceinline__ float exp2_fast(float x) {
  float r;
  asm("v_exp_f32 %0, %1" : "=v"(r) : "v"(x));
  return r;
}

__device__ __forceinline__ uu32 cvt_pk_bf16(float lo, float hi) {
  uu32 r;
  asm("v_cvt_pk_bf16_f32 %0, %1, %2" : "=v"(r) : "v"(lo), "v"(hi));
  return r;
}

// ---------------- cast hidden fp32 -> bf16 ----------------
__global__ void cast_x(const float* __restrict__ x, u16* __restrict__ xb, int n) {
  int i = (blockIdx.x * 256 + threadIdx.x) * 4;
  if (i >= n) return;
  float4 v = *(const float4*)(x + i);
  ushort4 o;
  o.x = f2bf(v.x); o.y = f2bf(v.y); o.z = f2bf(v.z); o.w = f2bf(v.w);
  *(ushort4*)(xb + i) = o;
}

// ---------------- mask * log2e ----------------
__global__ void mask_scale(const float* __restrict__ m, float* __restrict__ o, int n) {
  int i = blockIdx.x * 256 + threadIdx.x;
  if (i < n) o[i] = m[i] * LOG2E;
}

// ------------- transpose + cast W[k][n] -> Wt[n][k] bf16 -------------
__global__ void wtrans(const float* __restrict__ Wq, const float* __restrict__ Wk,
                       const float* __restrict__ Wv, u16* __restrict__ wt) {
  const float* W = blockIdx.z == 0 ? Wq : (blockIdx.z == 1 ? Wk : Wv);
  u16* out = wt + (size_t)blockIdx.z * HID_ * HID_;
  __shared__ float t[32][33];
  int tx = threadIdx.x & 31, ty = threadIdx.x >> 5;   // 32 x 8
  int k0 = blockIdx.x * 32, n0 = blockIdx.y * 32;
#pragma unroll
  for (int i = 0; i < 4; i++)
    t[ty + 8 * i][tx] = W[(k0 + ty + 8 * i) * HID_ + n0 + tx];
  __syncthreads();
#pragma unroll
  for (int i = 0; i < 4; i++)
    out[(n0 + ty + 8 * i) * HID_ + k0 + tx] = f2bf(t[tx][ty + 8 * i]);
}

// ---------------- QKV projection GEMM ----------------
// z=0: Q (pre-scaled by 0.125*log2e), z=1: K, both [b,h,s,d].
// z=2: V written DIRECTLY transposed as Vt [b,h,d,s].
__global__ __launch_bounds__(256) void qkv_gemm(
    const u16* __restrict__ xb, const u16* __restrict__ wt_all,
    const float* __restrict__ bq, const float* __restrict__ bk,
    const float* __restrict__ bv,
    u16* __restrict__ q, u16* __restrict__ k_, u16* __restrict__ vt) {
  int z = blockIdx.z;
  const u16* wt = wt_all + (size_t)z * HID_ * HID_;
  const float* bias = z == 0 ? bq : (z == 1 ? bk : bv);

  int l = threadIdx.x & 63, w = threadIdx.x >> 6;
  int lr = l & 15, lg = l >> 4;
  int m0 = blockIdx.x * 128 + w * 32;
  int n0 = blockIdx.y * 64;

  f32x4 acc[2][4] = {};
  const u16* arow0 = xb + (size_t)(m0 + lr) * HID_ + 8 * lg;
  const u16* arow1 = arow0 + 16 * HID_;
  const u16* brow[4];
#pragma unroll
  for (int nt = 0; nt < 4; nt++)
    brow[nt] = wt + (size_t)(n0 + 16 * nt + lr) * HID_ + 8 * lg;

#pragma unroll 4
  for (int kk = 0; kk < HID_; kk += 32) {
    bf16x8 a0 = *(const bf16x8*)(arow0 + kk);
    bf16x8 a1 = *(const bf16x8*)(arow1 + kk);
#pragma unroll
    for (int nt = 0; nt < 4; nt++) {
      bf16x8 b = *(const bf16x8*)(brow[nt] + kk);
      acc[0][nt] = __builtin_amdgcn_mfma_f32_16x16x32_bf16(a0, b, acc[0][nt], 0, 0, 0);
      acc[1][nt] = __builtin_amdgcn_mfma_f32_16x16x32_bf16(a1, b, acc[1][nt], 0, 0, 0);
    }
  }

  int h = blockIdx.y;
  if (z == 2) {
#pragma unroll
    for (int mt = 0; mt < 2; mt++)
#pragma unroll
      for (int nt = 0; nt < 4; nt++) {
        float bval = bias[n0 + 16 * nt + lr];
        int m = m0 + 16 * mt + 4 * lg;
        int bidx = m >> 11, s = m & 2047;
        int d = 16 * nt + lr;
        ushort4 pk;
        pk.x = f2bf(acc[mt][nt][0] + bval);
        pk.y = f2bf(acc[mt][nt][1] + bval);
        pk.z = f2bf(acc[mt][nt][2] + bval);
        pk.w = f2bf(acc[mt][nt][3] + bval);
        *(ushort4*)(vt + ((size_t)(bidx * NH_ + h) * HD_ + d) * S_ + s) = pk;
      }
  } else {
    u16* out = z == 0 ? q : k_;
    float osc = z == 0 ? QSCALE : 1.0f;
#pragma unroll
    for (int mt = 0; mt < 2; mt++)
#pragma unroll
      for (int nt = 0; nt < 4; nt++) {
        float bval = bias[n0 + 16 * nt + lr];
#pragma unroll
        for (int r = 0; r < 4; r++) {
          int m = m0 + 16 * mt + 4 * lg + r;
          int bidx = m >> 11, s = m & 2047;
          out[(((size_t)(bidx * NH_ + h)) * S_ + s) * HD_ + 16 * nt + lr] =
              f2bf((acc[mt][nt][r] + bval) * osc);
        }
      }
  }
}

// ---------------- flash attention: LDS-staged K/V, double-buffered ----------------
// 4 waves/block, 32 q-rows/wave (128/block), grid 768, KVBLK=64.
// K and Vt tiles staged to LDS once per BLOCK (reg-staged, loads issued at
// iter top, ds_write after compute -> global latency off the critical path).
// XOR swizzle (16B chunk ^ row&7) -> conflict-free ds_read_b128/b64.
// Swapped QK^T + shuffle-free pi-permuted PV (verified R4/R5).
__global__ __launch_bounds__(256) void attn6(
    const u16* __restrict__ q, const u16* __restrict__ k_,
    const u16* __restrict__ vt, const float* __restrict__ mask,
    float* __restrict__ out) {
  int id = blockIdx.x;
  int xcd = id & 7, ii = id >> 3;
  int bh = xcd * 6 + (ii >> 4);   // 6 heads per XCD -> K/V L2-resident
  int qb = ii & 15;
  int tid = threadIdx.x;
  int l = tid & 63, w = tid >> 6;
  int lr = l & 15, lg = l >> 4;
  int bidx = bh / NH_, h = bh % NH_;
  int q0 = qb * 128 + w * 32;

  // [buf][K=0/V=1][row][col] bf16, 32 KB; reused as epilogue f32 scratch
  __shared__ __align__(16) u16 kv_lds[2][2][64][64];

  const u16* qbase = q + ((size_t)bh * S_ + q0) * HD_;
  const u16* kbase = k_ + (size_t)bh * S_ * HD_;
  const u16* vtb = vt + (size_t)bh * HD_ * S_;
  const float* mrow = mask + (size_t)bidx * S_;

  bf16x8 aq[2][2];
#pragma unroll
  for (int qt = 0; qt < 2; qt++)
#pragma unroll
    for (int h2 = 0; h2 < 2; h2++)
      aq[qt][h2] = *(const bf16x8*)(qbase + (size_t)(16 * qt + lr) * HD_ + 8 * lg + 32 * h2);

  f32x4 ctx[2][4] = {};
  float mrun[2] = {-INFINITY, -INFINITY};
  float lpart[2] = {0.f, 0.f};

  // staging indices: thread covers two 16B chunks of each 8KB tile
  int i0 = tid, i1 = 256 + tid;
  int r0 = i0 >> 3, c0 = i0 & 7, r1 = i1 >> 3, c1 = i1 & 7;
  int d0k = r0 * 64 + ((c0 ^ (r0 & 7)) * 8);   // swizzled LDS elem offsets
  int d1k = r1 * 64 + ((c1 ^ (r1 & 7)) * 8);
  bf16x8 stK0, stK1, stV0, stV1;

  // prologue: stage tile 0 into buf 0
  stK0 = *(const bf16x8*)(kbase + i0 * 8);
  stK1 = *(const bf16x8*)(kbase + i1 * 8);
  stV0 = *(const bf16x8*)(vtb + r0 * S_ + c0 * 8);
  stV1 = *(const bf16x8*)(vtb + r1 * S_ + c1 * 8);
  *(bf16x8*)(&kv_lds[0][0][0][d0k]) = stK0;
  *(bf16x8*)(&kv_lds[0][0][0][d1k]) = stK1;
  *(bf16x8*)(&kv_lds[0][1][0][d0k]) = stV0;
  *(bf16x8*)(&kv_lds[0][1][0][d1k]) = stV1;
  __syncthreads();

  for (int it = 0; it < S_ / 64; ++it) {
    int buf = it & 1;
    int kb = it * 64;
    int kbn = (kb + 64) & (S_ - 1);   // wrap on last iter (harmless)

    // issue next-tile global loads EARLY (latency hides under compute)
    stK0 = *(const bf16x8*)(kbase + kbn * 64 + i0 * 8);
    stK1 = *(const bf16x8*)(kbase + kbn * 64 + i1 * 8);
    stV0 = *(const bf16x8*)(vtb + r0 * S_ + kbn + c0 * 8);
    stV1 = *(const bf16x8*)(vtb + r1 * S_ + kbn + c1 * 8);

    const u16* Kp = &kv_lds[buf][0][0][0];
    const u16* Vp = &kv_lds[buf][1][0][0];

    // K fragments from LDS (swizzled)
    bf16x8 kf[4][2];
#pragma unroll
    for (int nt = 0; nt < 4; nt++) {
      int row = 16 * nt + lr, sw = row & 7;
      const u16* krow = Kp + row * 64;
      kf[nt][0] = *(const bf16x8*)(krow + ((lg ^ sw) * 8));
      kf[nt][1] = *(const bf16x8*)(krow + (((4 + lg) ^ sw) * 8));
    }

    // QK^T swapped: sc[qt][nt][r] = P^T[kb+16nt+4lg+r][q0+16qt+lr]
    f32x4 sc[2][4] = {};
#pragma unroll
    for (int nt = 0; nt < 4; nt++)
#pragma unroll
      for (int qt = 0; qt < 2; qt++) {
        sc[qt][nt] = __builtin_amdgcn_mfma_f32_16x16x32_bf16(kf[nt][0], aq[qt][0], sc[qt][nt], 0, 0, 0);
        sc[qt][nt] = __builtin_amdgcn_mfma_f32_16x16x32_bf16(kf[nt][1], aq[qt][1], sc[qt][nt], 0, 0, 0);
      }

    // V^T A-fragments from LDS at pi-permuted columns (swizzled)
    union { bf16x8 v; bf16x4 h[2]; } vf[4][2];
#pragma unroll
    for (int nt = 0; nt < 4; nt++) {
      int row = 16 * nt + lr, sw = row & 7;
      const u16* vrow = Vp + row * 64;
      int off = (lg & 1) * 4, cb = lg >> 1;
      vf[nt][0].h[0] = *(const bf16x4*)(vrow + ((cb ^ sw) * 8) + off);
      vf[nt][0].h[1] = *(const bf16x4*)(vrow + (((2 + cb) ^ sw) * 8) + off);
      vf[nt][1].h[0] = *(const bf16x4*)(vrow + (((4 + cb) ^ sw) * 8) + off);
      vf[nt][1].h[1] = *(const bf16x4*)(vrow + (((6 + cb) ^ sw) * 8) + off);
    }

    f32x4 mk[4];
#pragma unroll
    for (int nt = 0; nt < 4; nt++)
      mk[nt] = *(const f32x4*)(mrow + kb + 16 * nt + 4 * lg);

    union { bf16x8 v; uu32 u[4]; } pb[2][2];

#pragma unroll
    for (int qt = 0; qt < 2; qt++) {
#pragma unroll
      for (int nt = 0; nt < 4; nt++)
#pragma unroll
        for (int r = 0; r < 4; r++)
          sc[qt][nt][r] = sc[qt][nt][r] + mk[nt][r];   // log2 domain

      float m0_ = fmaxf(fmaxf(sc[qt][0][0], sc[qt][0][1]), fmaxf(sc[qt][0][2], sc[qt][0][3]));
      float m1_ = fmaxf(fmaxf(sc[qt][1][0], sc[qt][1][1]), fmaxf(sc[qt][1][2], sc[qt][1][3]));
      float m2_ = fmaxf(fmaxf(sc[qt][2][0], sc[qt][2][1]), fmaxf(sc[qt][2][2], sc[qt][2][3]));
      float m3_ = fmaxf(fmaxf(sc[qt][3][0], sc[qt][3][1]), fmaxf(sc[qt][3][2], sc[qt][3][3]));
      float vmax = fmaxf(fmaxf(m0_, m1_), fmaxf(m2_, m3_));
      vmax = fmaxf(vmax, __shfl_xor(vmax, 16));
      vmax = fmaxf(vmax, __shfl_xor(vmax, 32));

      float mnew = fmaxf(mrun[qt], vmax);
      float scl = exp2_fast(mrun[qt] - mnew);
      mrun[qt] = mnew;
      lpart[qt] *= scl;

      float psum = 0.f;
#pragma unroll
      for (int nt = 0; nt < 4; nt++)
#pragma unroll
        for (int r = 0; r < 4; r++) {
          sc[qt][nt][r] = exp2_fast(sc[qt][nt][r] - mnew);
          psum += sc[qt][nt][r];
        }
      lpart[qt] += psum;

#pragma unroll
      for (int nt = 0; nt < 4; nt++)
        ctx[qt][nt] *= scl;

      // B-fragment = own registers under pi (no cross-lane)
#pragma unroll
      for (int h2 = 0; h2 < 2; h2++) {
        pb[qt][h2].u[0] = cvt_pk_bf16(sc[qt][2 * h2][0], sc[qt][2 * h2][1]);
        pb[qt][h2].u[1] = cvt_pk_bf16(sc[qt][2 * h2][2], sc[qt][2 * h2][3]);
        pb[qt][h2].u[2] = cvt_pk_bf16(sc[qt][2 * h2 + 1][0], sc[qt][2 * h2 + 1][1]);
        pb[qt][h2].u[3] = cvt_pk_bf16(sc[qt][2 * h2 + 1][2], sc[qt][2 * h2 + 1][3]);
      }
    }

    // PV: ctx^T[d][q] += V^T[d][pi(kv)] * P^T[pi(kv)][q]
#pragma unroll
    for (int nt = 0; nt < 4; nt++)
#pragma unroll
      for (int qt = 0; qt < 2; qt++) {
        ctx[qt][nt] = __builtin_amdgcn_mfma_f32_16x16x32_bf16(vf[nt][0].v, pb[qt][0].v, ctx[qt][nt], 0, 0, 0);
        ctx[qt][nt] = __builtin_amdgcn_mfma_f32_16x16x32_bf16(vf[nt][1].v, pb[qt][1].v, ctx[qt][nt], 0, 0, 0);
      }

    // write next tile into the other buffer (compute covered the load latency)
    int nb = buf ^ 1;
    *(bf16x8*)(&kv_lds[nb][0][0][d0k]) = stK0;
    *(bf16x8*)(&kv_lds[nb][0][0][d1k]) = stK1;
    *(bf16x8*)(&kv_lds[nb][1][0][d0k]) = stV0;
    *(bf16x8*)(&kv_lds[nb][1][0][d1k]) = stV1;
    __syncthreads();
  }

  // epilogue: reuse kv_lds as f32 scratch (barrier above guarantees no readers)
  float* ct = (float*)(&kv_lds[0][0][0][0]) + w * 1088;   // 16*68 per wave
#pragma unroll
  for (int qt = 0; qt < 2; qt++) {
    float lrun = lpart[qt];
    lrun += __shfl_xor(lrun, 16);
    lrun += __shfl_xor(lrun, 32);
    float inv = 1.f / lrun;
#pragma unroll
    for (int nt = 0; nt < 4; nt++) {
      f32x4 vv = ctx[qt][nt] * inv;
      *(f32x4*)(ct + lr * 68 + 16 * nt + 4 * lg) = vv;   // ct[q=lr][d]
    }
    __builtin_amdgcn_s_waitcnt(0);   // lgkm drain within wave before re-read
    float* ob = out + ((size_t)bidx * S_ + q0 + 16 * qt) * HID_ + h * HD_;
#pragma unroll
    for (int i = 0; i < 16; i++)
      ob[(size_t)i * HID_ + l] = ct[i * 68 + l];
  }
}

extern "C" void kernel_launch(void* const* d_in, const int* in_sizes, int n_in,
                              void* d_out, int out_size, void* d_ws, size_t ws_size,
                              hipStream_t stream) {
  const float* x    = (const float*)d_in[0];
  const float* mask = (const float*)d_in[1];
  const float* Wq   = (const float*)d_in[2];
  const float* bq   = (const float*)d_in[3];
  const float* Wk   = (const float*)d_in[4];
  const float* bk   = (const float*)d_in[5];
  const float* Wv   = (const float*)d_in[6];
  const float* bv   = (const float*)d_in[7];
  float* out = (float*)d_out;

  char* ws = (char*)d_ws;
  const size_t SZ_X  = (size_t)B_ * S_ * HID_ * 2;
  const size_t SZ_W  = (size_t)3 * HID_ * HID_ * 2;
  u16* xb = (u16*)ws;
  u16* wt = (u16*)(ws + SZ_X);
  u16* q  = (u16*)(ws + SZ_X + SZ_W);
  u16* k  = (u16*)(ws + SZ_X + SZ_W + SZ_X);
  u16* vt = (u16*)(ws + SZ_X + SZ_W + 2 * SZ_X);
  float* mskl = (float*)(ws + SZ_X + SZ_W + 3 * SZ_X);

  int n = B_ * S_ * HID_;
  hipLaunchKernelGGL(cast_x, dim3(n / 1024), dim3(256), 0, stream, x, xb, n);
  hipLaunchKernelGGL(mask_scale, dim3(B_ * S_ / 256), dim3(256), 0, stream,
                     mask, mskl, B_ * S_);
  hipLaunchKernelGGL(wtrans, dim3(24, 24, 3), dim3(256), 0, stream, Wq, Wk, Wv, wt);
  hipLaunchKernelGGL(qkv_gemm, dim3(64, 12, 3), dim3(256), 0, stream,
                     xb, wt, bq, bk, bv, q, k, vt);
  hipLaunchKernelGGL(attn6, dim3(768), dim3(256), 0, stream, q, k, vt, mskl, out);
}

// Round 7
// 165.560 us; speedup vs baseline: 4.1785x; 1.5668x over previous
//
#include <hip/hip_runtime.h>
#include <hip/hip_bf16.h>
#include <math.h>

#define B_ 4
#define S_ 2048
#define HID_ 768
#define NH_ 12
#define HD_ 64

typedef short bf16x8 __attribute__((ext_vector_type(8)));
typedef short bf16x4 __attribute__((ext_vector_type(4)));
typedef float f32x4 __attribute__((ext_vector_type(4)));
typedef unsigned short u16;
typedef unsigned int uu32;

#define QSCALE 0.18033688011112042f   /* 0.125 * log2(e) */
#define LOG2E  1.4426950408889634f

__device__ __forceinline__ u16 f2bf(float f) {
  union { float f; unsigned u; } x; x.f = f;
  unsigned u = x.u;
  u += 0x7FFFu + ((u >> 16) & 1u);   // round-to-nearest-even
  return (u16)(u >> 16);
}

__device__ __forceinline__ float exp2_fast(float x) {
  float r;
  asm("v_exp_f32 %0, %1" : "=v"(r) : "v"(x));
  return r;
}

__device__ __forceinline__ uu32 cvt_pk_bf16(float lo, float hi) {
  uu32 r;
  asm("v_cvt_pk_bf16_f32 %0, %1, %2" : "=v"(r) : "v"(lo), "v"(hi));
  return r;
}

// ---------------- cast hidden fp32 -> bf16 ----------------
__global__ void cast_x(const float* __restrict__ x, u16* __restrict__ xb, int n) {
  int i = (blockIdx.x * 256 + threadIdx.x) * 4;
  if (i >= n) return;
  float4 v = *(const float4*)(x + i);
  ushort4 o;
  o.x = f2bf(v.x); o.y = f2bf(v.y); o.z = f2bf(v.z); o.w = f2bf(v.w);
  *(ushort4*)(xb + i) = o;
}

// ---------------- mask * log2e ----------------
__global__ void mask_scale(const float* __restrict__ m, float* __restrict__ o, int n) {
  int i = blockIdx.x * 256 + threadIdx.x;
  if (i < n) o[i] = m[i] * LOG2E;
}

// ------------- transpose + cast W[k][n] -> Wt[n][k] bf16 -------------
__global__ void wtrans(const float* __restrict__ Wq, const float* __restrict__ Wk,
                       const float* __restrict__ Wv, u16* __restrict__ wt) {
  const float* W = blockIdx.z == 0 ? Wq : (blockIdx.z == 1 ? Wk : Wv);
  u16* out = wt + (size_t)blockIdx.z * HID_ * HID_;
  __shared__ float t[32][33];
  int tx = threadIdx.x & 31, ty = threadIdx.x >> 5;   // 32 x 8
  int k0 = blockIdx.x * 32, n0 = blockIdx.y * 32;
#pragma unroll
  for (int i = 0; i < 4; i++)
    t[ty + 8 * i][tx] = W[(k0 + ty + 8 * i) * HID_ + n0 + tx];
  __syncthreads();
#pragma unroll
  for (int i = 0; i < 4; i++)
    out[(n0 + ty + 8 * i) * HID_ + k0 + tx] = f2bf(t[tx][ty + 8 * i]);
}

// ---------------- fused QKV projection GEMM, LDS double-buffered ----------------
// C[8192 x 2304] = X[8192 x 768] * W^T[2304 x 768]^T, N = Q|K|V concatenated.
// 128x128 block tile, BK=32, 4 waves (2x2), reg-staged dbuf LDS (attn6 pattern).
// Rows padded to 40 elems (80B, 16B-aligned) -> 2-way bank alias = free.
// Epilogue: z=0 -> Q*QSCALE, z=1 -> K, z=2 -> V transposed [b,h,d,s]. Bias fused.
__global__ __launch_bounds__(256) void qkv_gemm2(
    const u16* __restrict__ xb, const u16* __restrict__ wt_all,
    const float* __restrict__ bq, const float* __restrict__ bk,
    const float* __restrict__ bv,
    u16* __restrict__ q, u16* __restrict__ k_, u16* __restrict__ vt) {
  int id = blockIdx.x;
  int xcd = id & 7, ii = id >> 3;        // 144 blocks per XCD
  int gid = xcd * 144 + ii;              // contiguous chunk per XCD (B-panels L2-resident)
  int bx = gid & 63, by = gid >> 6;      // bx: M-tile (64), by: N-tile (18)
  int z = by / 6;
  const float* bias = z == 0 ? bq : (z == 1 ? bk : bv);

  int tid = threadIdx.x;
  int l = tid & 63, w = tid >> 6;
  int lr = l & 15, lg = l >> 4;
  int wm = w >> 1, wn = w & 1;           // 2x2 wave grid, wave tile 64x64

  __shared__ __align__(16) u16 Al[2][128 * 40];
  __shared__ __align__(16) u16 Bl[2][128 * 40];

  const u16* Ab = xb + (size_t)bx * 128 * 768;
  const u16* Bb = wt_all + (size_t)by * 128 * 768;

  // staging: thread covers row sr, chunks sc & sc+1 (2 x 16B) of each tile
  int sr = tid >> 1, sc = (tid & 1) * 2;
  const u16* ag = Ab + sr * 768 + sc * 8;
  const u16* bg = Bb + sr * 768 + sc * 8;
  int woff = sr * 40 + sc * 8;

  // prologue: stage k-tile 0 into buf 0
  bf16x8 sA0 = *(const bf16x8*)(ag);
  bf16x8 sA1 = *(const bf16x8*)(ag + 8);
  bf16x8 sB0 = *(const bf16x8*)(bg);
  bf16x8 sB1 = *(const bf16x8*)(bg + 8);
  *(bf16x8*)(&Al[0][woff]) = sA0;
  *(bf16x8*)(&Al[0][woff + 8]) = sA1;
  *(bf16x8*)(&Bl[0][woff]) = sB0;
  *(bf16x8*)(&Bl[0][woff + 8]) = sB1;
  __syncthreads();

  f32x4 acc[4][4] = {};

#pragma unroll 1
  for (int t = 0; t < 23; ++t) {
    int cur = t & 1, nb = cur ^ 1;
    int k0 = (t + 1) * 32;
    // issue next-tile global loads EARLY
    sA0 = *(const bf16x8*)(ag + k0);
    sA1 = *(const bf16x8*)(ag + k0 + 8);
    sB0 = *(const bf16x8*)(bg + k0);
    sB1 = *(const bf16x8*)(bg + k0 + 8);

    bf16x8 af[4], bf[4];
#pragma unroll
    for (int mt = 0; mt < 4; mt++)
      af[mt] = *(const bf16x8*)(&Al[cur][(64 * wm + 16 * mt + lr) * 40 + lg * 8]);
#pragma unroll
    for (int nt = 0; nt < 4; nt++)
      bf[nt] = *(const bf16x8*)(&Bl[cur][(64 * wn + 16 * nt + lr) * 40 + lg * 8]);
#pragma unroll
    for (int mt = 0; mt < 4; mt++)
#pragma unroll
      for (int nt = 0; nt < 4; nt++)
        acc[mt][nt] = __builtin_amdgcn_mfma_f32_16x16x32_bf16(af[mt], bf[nt], acc[mt][nt], 0, 0, 0);

    // write next tile (compute covered global latency)
    *(bf16x8*)(&Al[nb][woff]) = sA0;
    *(bf16x8*)(&Al[nb][woff + 8]) = sA1;
    *(bf16x8*)(&Bl[nb][woff]) = sB0;
    *(bf16x8*)(&Bl[nb][woff + 8]) = sB1;
    __syncthreads();
  }
  // epilogue K-step (buf 1, t=23)
  {
    bf16x8 af[4], bf[4];
#pragma unroll
    for (int mt = 0; mt < 4; mt++)
      af[mt] = *(const bf16x8*)(&Al[1][(64 * wm + 16 * mt + lr) * 40 + lg * 8]);
#pragma unroll
    for (int nt = 0; nt < 4; nt++)
      bf[nt] = *(const bf16x8*)(&Bl[1][(64 * wn + 16 * nt + lr) * 40 + lg * 8]);
#pragma unroll
    for (int mt = 0; mt < 4; mt++)
#pragma unroll
      for (int nt = 0; nt < 4; nt++)
        acc[mt][nt] = __builtin_amdgcn_mfma_f32_16x16x32_bf16(af[mt], bf[nt], acc[mt][nt], 0, 0, 0);
  }

  // epilogue: h = 2*(by%6) + wn, d = 16*nt + lr; s = m & 2047
  int hh = 2 * (by % 6) + wn;
  int mbase = bx * 128 + 64 * wm;
  int bidx = mbase >> 11;
  float osc = z == 0 ? QSCALE : 1.0f;
#pragma unroll
  for (int mt = 0; mt < 4; mt++)
#pragma unroll
    for (int nt = 0; nt < 4; nt++) {
      int d = 16 * nt + lr;
      float bval = bias[(by % 6) * 128 + 64 * wn + d];
      int s = (mbase + 16 * mt + 4 * lg) & 2047;
      if (z == 2) {
        ushort4 pk;
        pk.x = f2bf(acc[mt][nt][0] + bval);
        pk.y = f2bf(acc[mt][nt][1] + bval);
        pk.z = f2bf(acc[mt][nt][2] + bval);
        pk.w = f2bf(acc[mt][nt][3] + bval);
        *(ushort4*)(vt + ((size_t)(bidx * NH_ + hh) * HD_ + d) * S_ + s) = pk;
      } else {
        u16* o = z == 0 ? q : k_;
#pragma unroll
        for (int r = 0; r < 4; r++)
          o[((size_t)(bidx * NH_ + hh) * S_ + s + r) * HD_ + d] =
              f2bf((acc[mt][nt][r] + bval) * osc);
      }
    }
}

// ---------------- flash attention: LDS-staged K/V, double-buffered ----------------
// (unchanged from R6 — 259us total, attn ~85us)
__global__ __launch_bounds__(256) void attn6(
    const u16* __restrict__ q, const u16* __restrict__ k_,
    const u16* __restrict__ vt, const float* __restrict__ mask,
    float* __restrict__ out) {
  int id = blockIdx.x;
  int xcd = id & 7, ii = id >> 3;
  int bh = xcd * 6 + (ii >> 4);   // 6 heads per XCD -> K/V L2-resident
  int qb = ii & 15;
  int tid = threadIdx.x;
  int l = tid & 63, w = tid >> 6;
  int lr = l & 15, lg = l >> 4;
  int bidx = bh / NH_, h = bh % NH_;
  int q0 = qb * 128 + w * 32;

  __shared__ __align__(16) u16 kv_lds[2][2][64][64];

  const u16* qbase = q + ((size_t)bh * S_ + q0) * HD_;
  const u16* kbase = k_ + (size_t)bh * S_ * HD_;
  const u16* vtb = vt + (size_t)bh * HD_ * S_;
  const float* mrow = mask + (size_t)bidx * S_;

  bf16x8 aq[2][2];
#pragma unroll
  for (int qt = 0; qt < 2; qt++)
#pragma unroll
    for (int h2 = 0; h2 < 2; h2++)
      aq[qt][h2] = *(const bf16x8*)(qbase + (size_t)(16 * qt + lr) * HD_ + 8 * lg + 32 * h2);

  f32x4 ctx[2][4] = {};
  float mrun[2] = {-INFINITY, -INFINITY};
  float lpart[2] = {0.f, 0.f};

  int i0 = tid, i1 = 256 + tid;
  int r0 = i0 >> 3, c0 = i0 & 7, r1 = i1 >> 3, c1 = i1 & 7;
  int d0k = r0 * 64 + ((c0 ^ (r0 & 7)) * 8);
  int d1k = r1 * 64 + ((c1 ^ (r1 & 7)) * 8);
  bf16x8 stK0, stK1, stV0, stV1;

  stK0 = *(const bf16x8*)(kbase + i0 * 8);
  stK1 = *(const bf16x8*)(kbase + i1 * 8);
  stV0 = *(const bf16x8*)(vtb + r0 * S_ + c0 * 8);
  stV1 = *(const bf16x8*)(vtb + r1 * S_ + c1 * 8);
  *(bf16x8*)(&kv_lds[0][0][0][d0k]) = stK0;
  *(bf16x8*)(&kv_lds[0][0][0][d1k]) = stK1;
  *(bf16x8*)(&kv_lds[0][1][0][d0k]) = stV0;
  *(bf16x8*)(&kv_lds[0][1][0][d1k]) = stV1;
  __syncthreads();

  for (int it = 0; it < S_ / 64; ++it) {
    int buf = it & 1;
    int kb = it * 64;
    int kbn = (kb + 64) & (S_ - 1);

    stK0 = *(const bf16x8*)(kbase + kbn * 64 + i0 * 8);
    stK1 = *(const bf16x8*)(kbase + kbn * 64 + i1 * 8);
    stV0 = *(const bf16x8*)(vtb + r0 * S_ + kbn + c0 * 8);
    stV1 = *(const bf16x8*)(vtb + r1 * S_ + kbn + c1 * 8);

    const u16* Kp = &kv_lds[buf][0][0][0];
    const u16* Vp = &kv_lds[buf][1][0][0];

    bf16x8 kf[4][2];
#pragma unroll
    for (int nt = 0; nt < 4; nt++) {
      int row = 16 * nt + lr, sw = row & 7;
      const u16* krow = Kp + row * 64;
      kf[nt][0] = *(const bf16x8*)(krow + ((lg ^ sw) * 8));
      kf[nt][1] = *(const bf16x8*)(krow + (((4 + lg) ^ sw) * 8));
    }

    f32x4 sc[2][4] = {};
#pragma unroll
    for (int nt = 0; nt < 4; nt++)
#pragma unroll
      for (int qt = 0; qt < 2; qt++) {
        sc[qt][nt] = __builtin_amdgcn_mfma_f32_16x16x32_bf16(kf[nt][0], aq[qt][0], sc[qt][nt], 0, 0, 0);
        sc[qt][nt] = __builtin_amdgcn_mfma_f32_16x16x32_bf16(kf[nt][1], aq[qt][1], sc[qt][nt], 0, 0, 0);
      }

    union { bf16x8 v; bf16x4 h[2]; } vf[4][2];
#pragma unroll
    for (int nt = 0; nt < 4; nt++) {
      int row = 16 * nt + lr, sw = row & 7;
      const u16* vrow = Vp + row * 64;
      int off = (lg & 1) * 4, cb = lg >> 1;
      vf[nt][0].h[0] = *(const bf16x4*)(vrow + ((cb ^ sw) * 8) + off);
      vf[nt][0].h[1] = *(const bf16x4*)(vrow + (((2 + cb) ^ sw) * 8) + off);
      vf[nt][1].h[0] = *(const bf16x4*)(vrow + (((4 + cb) ^ sw) * 8) + off);
      vf[nt][1].h[1] = *(const bf16x4*)(vrow + (((6 + cb) ^ sw) * 8) + off);
    }

    f32x4 mk[4];
#pragma unroll
    for (int nt = 0; nt < 4; nt++)
      mk[nt] = *(const f32x4*)(mrow + kb + 16 * nt + 4 * lg);

    union { bf16x8 v; uu32 u[4]; } pb[2][2];

#pragma unroll
    for (int qt = 0; qt < 2; qt++) {
#pragma unroll
      for (int nt = 0; nt < 4; nt++)
#pragma unroll
        for (int r = 0; r < 4; r++)
          sc[qt][nt][r] = sc[qt][nt][r] + mk[nt][r];

      float m0_ = fmaxf(fmaxf(sc[qt][0][0], sc[qt][0][1]), fmaxf(sc[qt][0][2], sc[qt][0][3]));
      float m1_ = fmaxf(fmaxf(sc[qt][1][0], sc[qt][1][1]), fmaxf(sc[qt][1][2], sc[qt][1][3]));
      float m2_ = fmaxf(fmaxf(sc[qt][2][0], sc[qt][2][1]), fmaxf(sc[qt][2][2], sc[qt][2][3]));
      float m3_ = fmaxf(fmaxf(sc[qt][3][0], sc[qt][3][1]), fmaxf(sc[qt][3][2], sc[qt][3][3]));
      float vmax = fmaxf(fmaxf(m0_, m1_), fmaxf(m2_, m3_));
      vmax = fmaxf(vmax, __shfl_xor(vmax, 16));
      vmax = fmaxf(vmax, __shfl_xor(vmax, 32));

      float mnew = fmaxf(mrun[qt], vmax);
      float scl = exp2_fast(mrun[qt] - mnew);
      mrun[qt] = mnew;
      lpart[qt] *= scl;

      float psum = 0.f;
#pragma unroll
      for (int nt = 0; nt < 4; nt++)
#pragma unroll
        for (int r = 0; r < 4; r++) {
          sc[qt][nt][r] = exp2_fast(sc[qt][nt][r] - mnew);
          psum += sc[qt][nt][r];
        }
      lpart[qt] += psum;

#pragma unroll
      for (int nt = 0; nt < 4; nt++)
        ctx[qt][nt] *= scl;

#pragma unroll
      for (int h2 = 0; h2 < 2; h2++) {
        pb[qt][h2].u[0] = cvt_pk_bf16(sc[qt][2 * h2][0], sc[qt][2 * h2][1]);
        pb[qt][h2].u[1] = cvt_pk_bf16(sc[qt][2 * h2][2], sc[qt][2 * h2][3]);
        pb[qt][h2].u[2] = cvt_pk_bf16(sc[qt][2 * h2 + 1][0], sc[qt][2 * h2 + 1][1]);
        pb[qt][h2].u[3] = cvt_pk_bf16(sc[qt][2 * h2 + 1][2], sc[qt][2 * h2 + 1][3]);
      }
    }

#pragma unroll
    for (int nt = 0; nt < 4; nt++)
#pragma unroll
      for (int qt = 0; qt < 2; qt++) {
        ctx[qt][nt] = __builtin_amdgcn_mfma_f32_16x16x32_bf16(vf[nt][0].v, pb[qt][0].v, ctx[qt][nt], 0, 0, 0);
        ctx[qt][nt] = __builtin_amdgcn_mfma_f32_16x16x32_bf16(vf[nt][1].v, pb[qt][1].v, ctx[qt][nt], 0, 0, 0);
      }

    int nb = buf ^ 1;
    *(bf16x8*)(&kv_lds[nb][0][0][d0k]) = stK0;
    *(bf16x8*)(&kv_lds[nb][0][0][d1k]) = stK1;
    *(bf16x8*)(&kv_lds[nb][1][0][d0k]) = stV0;
    *(bf16x8*)(&kv_lds[nb][1][0][d1k]) = stV1;
    __syncthreads();
  }

  float* ct = (float*)(&kv_lds[0][0][0][0]) + w * 1088;
#pragma unroll
  for (int qt = 0; qt < 2; qt++) {
    float lrun = lpart[qt];
    lrun += __shfl_xor(lrun, 16);
    lrun += __shfl_xor(lrun, 32);
    float inv = 1.f / lrun;
#pragma unroll
    for (int nt = 0; nt < 4; nt++) {
      f32x4 vv = ctx[qt][nt] * inv;
      *(f32x4*)(ct + lr * 68 + 16 * nt + 4 * lg) = vv;
    }
    __builtin_amdgcn_s_waitcnt(0);
    float* ob = out + ((size_t)bidx * S_ + q0 + 16 * qt) * HID_ + h * HD_;
#pragma unroll
    for (int i = 0; i < 16; i++)
      ob[(size_t)i * HID_ + l] = ct[i * 68 + l];
  }
}

extern "C" void kernel_launch(void* const* d_in, const int* in_sizes, int n_in,
                              void* d_out, int out_size, void* d_ws, size_t ws_size,
                              hipStream_t stream) {
  const float* x    = (const float*)d_in[0];
  const float* mask = (const float*)d_in[1];
  const float* Wq   = (const float*)d_in[2];
  const float* bq   = (const float*)d_in[3];
  const float* Wk   = (const float*)d_in[4];
  const float* bk   = (const float*)d_in[5];
  const float* Wv   = (const float*)d_in[6];
  const float* bv   = (const float*)d_in[7];
  float* out = (float*)d_out;

  char* ws = (char*)d_ws;
  const size_t SZ_X  = (size_t)B_ * S_ * HID_ * 2;
  const size_t SZ_W  = (size_t)3 * HID_ * HID_ * 2;
  u16* xb = (u16*)ws;
  u16* wt = (u16*)(ws + SZ_X);
  u16* q  = (u16*)(ws + SZ_X + SZ_W);
  u16* k  = (u16*)(ws + SZ_X + SZ_W + SZ_X);
  u16* vt = (u16*)(ws + SZ_X + SZ_W + 2 * SZ_X);
  float* mskl = (float*)(ws + SZ_X + SZ_W + 3 * SZ_X);

  int n = B_ * S_ * HID_;
  hipLaunchKernelGGL(cast_x, dim3(n / 1024), dim3(256), 0, stream, x, xb, n);
  hipLaunchKernelGGL(mask_scale, dim3(B_ * S_ / 256), dim3(256), 0, stream,
                     mask, mskl, B_ * S_);
  hipLaunchKernelGGL(wtrans, dim3(24, 24, 3), dim3(256), 0, stream, Wq, Wk, Wv, wt);
  hipLaunchKernelGGL(qkv_gemm2, dim3(1152), dim3(256), 0, stream,
                     xb, wt, bq, bk, bv, q, k, vt);
  hipLaunchKernelGGL(attn6, dim3(768), dim3(256), 0, stream, q, k, vt, mskl, out);
}